// Round 3
// baseline (1197.148 us; speedup 1.0000x reference)
//
#include <hip/hip_runtime.h>
#include <math.h>

typedef __attribute__((ext_vector_type(4))) float f32x4;
typedef __attribute__((ext_vector_type(8))) short bf16x8;

__device__ inline short f2bf(float f) {
    union { float f; unsigned u; } v; v.f = f;
    unsigned u = v.u;
    u += 0x7fffu + ((u >> 16) & 1u);   // RNE
    return (short)(u >> 16);
}

// workspace layout (floats)
#define WS_ALTX 0
#define WS_SBUF 65536
#define WS_Y    131072
#define WS_IMV  196608
#define WS_QKV  262144      // 196608 floats
#define WS_H    458752      // 262144 floats
#define WS_CNT  720896      // 16 ints

struct P {
    const float* W; const float* A; float* out;
    int N, K, NX, NS;
    int* cnt;
    const float* g1; const float* b1; const float* g2; const float* b2;
    const float* fc1_b; const float* fc2_b;
    float* sbuf; float* y; float* qkv; float* imv; float* h; float* outF;
    int a;
    float* zbuf; int z4;     // extra blocks zero z4 float4s of zbuf
};

// ---------------- init: avgpool + sinus bias + zero counters/qkv/h ----------------
__global__ __launch_bounds__(256) void k_init(const float* __restrict__ x, float* __restrict__ ws) {
    int blk = blockIdx.x, t = threadIdx.x;
    float* altx = ws + WS_ALTX;
    float* sbuf = ws + WS_SBUF;
    if (blk < 512) {
        int wv = t >> 6, lane = t & 63;
        int p = blk * 4 + wv;              // p = c2*64 + c1
        const float* row = x + (size_t)p * 2048;
        int c2 = p >> 6, c1 = p & 63;
        int m = c1 * 32 + c2;
        for (int seg = 0; seg < 32; ++seg) {
            float v = row[seg * 64 + lane];
            for (int off = 32; off; off >>= 1) v += __shfl_xor(v, off, 64);
            if (lane == 0) altx[seg * 2048 + m] = v * (1.0f / 64.0f);
        }
    } else if (blk < 544) {
        int i = blk - 512;
        const float kln = logf(10000.0f) / 1024.0f;
        for (int l = t; l < 2048; l += 256) {
            int c = l & ~1;
            float ang = (float)i * expf(-(float)c * kln);
            sbuf[i * 2048 + l] = (l & 1) ? cosf(ang) : sinf(ang);
        }
    } else if (blk == 544) {
        if (t < 16) ((int*)(ws + WS_CNT))[t] = 0;
    } else if (blk < 569) {                 // zero qkv: 49152 f4 over 24 blocks
        float4* zp = (float4*)(ws + WS_QKV);
        float4 z = {0.f,0.f,0.f,0.f};
        int base = (blk - 545) * 2048;
        #pragma unroll
        for (int j = 0; j < 8; ++j) zp[base + t + j * 256] = z;
    } else {                                // blocks 569..600 zero h: 65536 f4 / 32
        float4* zp = (float4*)(ws + WS_H);
        float4 z = {0.f,0.f,0.f,0.f};
        int base = (blk - 569) * 2048;
        #pragma unroll
        for (int j = 0; j < 8; ++j) zp[base + t + j * 256] = z;
    }
}

// block-wide (sm,ss) reduction, 256 threads
__device__ inline void red2(float& sm, float& ss) {
    for (int off = 32; off; off >>= 1) {
        sm += __shfl_xor(sm, off, 64);
        ss += __shfl_xor(ss, off, 64);
    }
    __shared__ float ra[4], rb[4];
    int wv = threadIdx.x >> 6, lane = threadIdx.x & 63;
    if (lane == 0) { ra[wv] = sm; rb[wv] = ss; }
    __syncthreads();
    sm = ra[0] + ra[1] + ra[2] + ra[3];
    ss = rb[0] + rb[1] + rb[2] + rb[3];
}

// TAIL ids: 0 none, 1 LN1(sbuf->y), 2 scan(qkv->imv), 3 LN2 in-place(sbuf),
//           4 gelu(h)+zero sbuf, 5 sbuf+=fc2_b then LN1->y (or ->outF at a==2)
template<int NIT, int TAIL>
__global__ __launch_bounds__(256, 2) void k_gemm(P p) {
    int t = threadIdx.x;

    if ((int)blockIdx.y >= p.NS) {          // zero-extra blocks
        int per = (p.z4 + p.NX - 1) / p.NX;
        float4* zp = (float4*)p.zbuf;
        float4 z = {0.f,0.f,0.f,0.f};
        int base = blockIdx.x * per, end = min(base + per, p.z4);
        for (int i = base + t; i < end; i += 256) zp[i] = z;
        return;
    }

    {   // ---- GEMM phase (unchanged core) ----
        int lane = t & 63, wv = t >> 6;
        int m = lane & 15, q = lane >> 4;
        int nb = blockIdx.x * 64 + wv * 16;
        int K = p.K, N = p.N;
        size_t kbeg = (size_t)blockIdx.y * (NIT * 32);
        const float* A0 = p.A + (size_t)m * K + kbeg + q * 8;
        const float* A1 = A0 + (size_t)16 * K;
        const float* B  = p.W + (size_t)(nb + m) * K + kbeg + q * 8;
        f32x4 acc0 = {0.f,0.f,0.f,0.f};
        f32x4 acc1 = {0.f,0.f,0.f,0.f};
        float4 a0l = *(const float4*)(A0);
        float4 a0h = *(const float4*)(A0 + 4);
        float4 a1l = *(const float4*)(A1);
        float4 a1h = *(const float4*)(A1 + 4);
        float4 bl  = *(const float4*)(B);
        float4 bh  = *(const float4*)(B + 4);
        #pragma unroll
        for (int it = 0; it < NIT; ++it) {
            float4 c0l = a0l, c0h = a0h, c1l = a1l, c1h = a1h, cbl = bl, cbh = bh;
            if (it + 1 < NIT) {
                int k = (it + 1) * 32;
                a0l = *(const float4*)(A0 + k);
                a0h = *(const float4*)(A0 + k + 4);
                a1l = *(const float4*)(A1 + k);
                a1h = *(const float4*)(A1 + k + 4);
                bl  = *(const float4*)(B + k);
                bh  = *(const float4*)(B + k + 4);
            }
            bf16x8 fa0 = { f2bf(c0l.x), f2bf(c0l.y), f2bf(c0l.z), f2bf(c0l.w),
                           f2bf(c0h.x), f2bf(c0h.y), f2bf(c0h.z), f2bf(c0h.w) };
            bf16x8 fa1 = { f2bf(c1l.x), f2bf(c1l.y), f2bf(c1l.z), f2bf(c1l.w),
                           f2bf(c1h.x), f2bf(c1h.y), f2bf(c1h.z), f2bf(c1h.w) };
            bf16x8 fb  = { f2bf(cbl.x), f2bf(cbl.y), f2bf(cbl.z), f2bf(cbl.w),
                           f2bf(cbh.x), f2bf(cbh.y), f2bf(cbh.z), f2bf(cbh.w) };
            acc0 = __builtin_amdgcn_mfma_f32_16x16x32_bf16(fa0, fb, acc0, 0, 0, 0);
            acc1 = __builtin_amdgcn_mfma_f32_16x16x32_bf16(fa1, fb, acc1, 0, 0, 0);
        }
        float* op = p.out + (size_t)(q * 4) * N + nb + m;
        #pragma unroll
        for (int r = 0; r < 4; ++r) {
            atomicAdd(op + (size_t)r * N, acc0[r]);
            atomicAdd(op + (size_t)(r + 16) * N, acc1[r]);
        }
    }

    // ---- release ----
    __syncthreads();
    if (t == 0) {
        __threadfence();
        __hip_atomic_fetch_add(p.cnt, 1, __ATOMIC_RELEASE, __HIP_MEMORY_SCOPE_AGENT);
    }
    if (TAIL == 0) return;

    constexpr int NTAIL = (TAIL == 2) ? 16 : (TAIL == 4) ? 64 : 32;
    if (blockIdx.y != 0 || (int)blockIdx.x >= NTAIL) return;

    // ---- acquire: wait for all gemm blocks of this dispatch ----
    int target = p.NX * p.NS;
    if (t == 0) {
        while (__hip_atomic_load(p.cnt, __ATOMIC_ACQUIRE, __HIP_MEMORY_SCOPE_AGENT) < target)
            __builtin_amdgcn_s_sleep(8);
    }
    __syncthreads();
    __threadfence();

    // ---- tail work ----
    if (TAIL == 1 || TAIL == 3 || TAIL == 5) {      // per-row LN variants
        int r = blockIdx.x;
        const float* row = p.sbuf + r * 2048;
        float vv[8], sm = 0.f, ss = 0.f;
        #pragma unroll
        for (int j = 0; j < 8; ++j) {
            int idx = t + j * 256;
            float v = row[idx];
            if (TAIL == 5) v += p.fc2_b[idx];
            vv[j] = v; sm += v; ss += v * v;
        }
        red2(sm, ss);
        float mu = sm * (1.0f / 2048.0f);
        float rstd = rsqrtf(ss * (1.0f / 2048.0f) - mu * mu + 1e-5f);
        if (TAIL == 5 && p.a == 2) {
            #pragma unroll
            for (int j = 0; j < 8; ++j) p.outF[r * 2048 + t + j * 256] = vv[j];
        } else {
            #pragma unroll
            for (int j = 0; j < 8; ++j) {
                int idx = t + j * 256;
                float v = vv[j];
                float ln1 = (v - mu) * rstd * p.g1[idx] + p.b1[idx];
                if (TAIL == 1) p.y[r * 2048 + idx] = ln1;
                if (TAIL == 3) p.sbuf[r * 2048 + idx] = (v - mu) * rstd * p.g2[idx] + p.b2[idx] + v;
                if (TAIL == 5) { p.sbuf[r * 2048 + idx] = v; p.y[r * 2048 + idx] = ln1; }
            }
        }
    }
    if (TAIL == 2) {                                 // scalar attn + serial scan
        int hd = blockIdx.x;
        __shared__ float rsa[32];
        if (t < 32) {
            const float* qr = p.qkv + (size_t)t * 6144 + hd * 128;
            const float* kr = qr + 2048;
            float acc = 0.f;
            for (int d = 0; d < 128; ++d) acc += qr[d] * kr[d];
            rsa[t] = acc * 0.08838834764831845f;
        }
        __syncthreads();
        if (t < 128) {
            float acc = 0.f;
            for (int i = 0; i < 32; ++i) {
                acc += rsa[i] * p.qkv[(size_t)i * 6144 + 4096 + hd * 128 + t];
                p.imv[i * 2048 + hd * 128 + t] = acc;
            }
        }
    }
    if (TAIL == 4) {                                 // gelu(h+fc1_b) + zero sbuf
        int b = blockIdx.x;
        size_t base = (size_t)b * 4096;
        #pragma unroll
        for (int j = 0; j < 16; ++j) {
            size_t idx = base + t + j * 256;
            float v = p.h[idx] + p.fc1_b[idx & 8191];
            p.h[idx] = 0.5f * v * (1.0f + erff(v * 0.70710678118654752f));
        }
        float4* zp = (float4*)p.sbuf;
        float4 z = {0.f,0.f,0.f,0.f};
        zp[b * 256 + t] = z;
    }
}

extern "C" void kernel_launch(void* const* d_in, const int* in_sizes, int n_in,
                              void* d_out, int out_size, void* d_ws, size_t ws_size,
                              hipStream_t stream) {
    const float* x      = (const float*)d_in[0];
    const float* weight = (const float*)d_in[1];
    const float* Wqkv   = (const float*)d_in[2];
    const float* Wo     = (const float*)d_in[3];
    const float* ln1_g  = (const float*)d_in[4];
    const float* ln1_b  = (const float*)d_in[5];
    const float* ln2_g  = (const float*)d_in[6];
    const float* ln2_b  = (const float*)d_in[7];
    const float* fc1_w  = (const float*)d_in[8];
    const float* fc1_b  = (const float*)d_in[9];
    const float* fc2_w  = (const float*)d_in[10];
    const float* fc2_b  = (const float*)d_in[11];
    float* ws = (float*)d_ws;
    int* cnt = (int*)(ws + WS_CNT);

    P base{};
    base.g1 = ln1_g; base.b1 = ln1_b; base.g2 = ln2_g; base.b2 = ln2_b;
    base.fc1_b = fc1_b; base.fc2_b = fc2_b;
    base.sbuf = ws + WS_SBUF; base.y = ws + WS_Y; base.qkv = ws + WS_QKV;
    base.imv = ws + WS_IMV; base.h = ws + WS_H; base.outF = (float*)d_out;

    k_init<<<601, 256, 0, stream>>>(x, ws);

    P p = base;                                     // D1: s += weight @ altx ; tail LN1
    p.W = weight; p.A = ws + WS_ALTX; p.out = ws + WS_SBUF;
    p.N = 2048; p.K = 2048; p.NX = 32; p.NS = 8; p.cnt = cnt + 0; p.z4 = 0;
    k_gemm<8, 1><<<dim3(32, 8), 256, 0, stream>>>(p);

    for (int a = 0; a < 3; ++a) {
        P q = base; q.a = a;                        // D2: qkv += Wqkv @ y ; tail scan ; extra: zero h (a>0)
        q.W = Wqkv + (size_t)a * 12582912; q.A = ws + WS_Y; q.out = ws + WS_QKV;
        q.N = 6144; q.K = 2048; q.NX = 96; q.NS = 8; q.cnt = cnt + 1 + a * 4;
        q.zbuf = ws + WS_H; q.z4 = (a > 0) ? 65536 : 0;
        k_gemm<8, 2><<<dim3(96, 8 + (q.z4 ? 1 : 0)), 256, 0, stream>>>(q);

        P w = base; w.a = a;                        // D3: sbuf += Wo @ imv ; tail LN2-residual
        w.W = Wo + (size_t)a * 4194304; w.A = ws + WS_IMV; w.out = ws + WS_SBUF;
        w.N = 2048; w.K = 2048; w.NX = 32; w.NS = 8; w.cnt = cnt + 2 + a * 4; w.z4 = 0;
        k_gemm<8, 3><<<dim3(32, 8), 256, 0, stream>>>(w);

        P f1 = base; f1.a = a;                      // D4: h += fc1 @ sbuf ; tail gelu+zero sbuf ; extra: zero qkv (a<2)
        f1.W = fc1_w; f1.A = ws + WS_SBUF; f1.out = ws + WS_H;
        f1.N = 8192; f1.K = 2048; f1.NX = 128; f1.NS = 8; f1.cnt = cnt + 3 + a * 4;
        f1.zbuf = ws + WS_QKV; f1.z4 = (a < 2) ? 49152 : 0;
        k_gemm<8, 4><<<dim3(128, 8 + (f1.z4 ? 1 : 0)), 256, 0, stream>>>(f1);

        P f2 = base; f2.a = a;                      // D5: sbuf += fc2 @ h ; tail bias(+LN1 or out)
        f2.W = fc2_w; f2.A = ws + WS_H; f2.out = ws + WS_SBUF;
        f2.N = 2048; f2.K = 8192; f2.NX = 32; f2.NS = 32; f2.cnt = cnt + 4 + a * 4; f2.z4 = 0;
        k_gemm<8, 5><<<dim3(32, 32), 256, 0, stream>>>(f2);
    }
}

// Round 4
// 813.396 us; speedup vs baseline: 1.4718x; 1.4718x over previous
//
#include <hip/hip_runtime.h>
#include <math.h>

typedef __attribute__((ext_vector_type(4))) float f32x4;
typedef __attribute__((ext_vector_type(8))) short bf16x8;

__device__ inline short f2bf(float f) {
    union { float f; unsigned u; } v; v.f = f;
    unsigned u = v.u;
    u += 0x7fffu + ((u >> 16) & 1u);   // RNE
    return (short)(u >> 16);
}

// workspace layout (floats)
#define WS_ALTX 0
#define WS_SBUF 65536
#define WS_Y    131072
#define WS_IMV  196608
#define WS_QKV  262144      // 196608 floats
#define WS_H    458752      // 262144 floats
#define WS_CNT  720896      // 16 ints

struct P {
    const float* W; const float* A; float* out;
    int N, K, NX, NS;
    int* cnt;
    const float* g1; const float* b1; const float* g2; const float* b2;
    const float* fc1_b; const float* fc2_b;
    float* sbuf; float* y; float* qkv; float* imv; float* h; float* outF;
    int a;
    float* zbuf; int z4;     // extra blocks zero z4 float4s of zbuf
};

// ---------------- init: avgpool + sinus bias + zero counters/qkv/h ----------------
__global__ __launch_bounds__(256) void k_init(const float* __restrict__ x, float* __restrict__ ws) {
    int blk = blockIdx.x, t = threadIdx.x;
    float* altx = ws + WS_ALTX;
    float* sbuf = ws + WS_SBUF;
    if (blk < 512) {
        int wv = t >> 6, lane = t & 63;
        int p = blk * 4 + wv;              // p = c2*64 + c1
        const float* row = x + (size_t)p * 2048;
        int c2 = p >> 6, c1 = p & 63;
        int m = c1 * 32 + c2;
        for (int seg = 0; seg < 32; ++seg) {
            float v = row[seg * 64 + lane];
            for (int off = 32; off; off >>= 1) v += __shfl_xor(v, off, 64);
            if (lane == 0) altx[seg * 2048 + m] = v * (1.0f / 64.0f);
        }
    } else if (blk < 544) {
        int i = blk - 512;
        const float kln = logf(10000.0f) / 1024.0f;
        for (int l = t; l < 2048; l += 256) {
            int c = l & ~1;
            float ang = (float)i * expf(-(float)c * kln);
            sbuf[i * 2048 + l] = (l & 1) ? cosf(ang) : sinf(ang);
        }
    } else if (blk == 544) {
        if (t < 16) ((int*)(ws + WS_CNT))[t] = 0;
    } else if (blk < 569) {                 // zero qkv: 49152 f4 over 24 blocks
        float4* zp = (float4*)(ws + WS_QKV);
        float4 z = {0.f,0.f,0.f,0.f};
        int base = (blk - 545) * 2048;
        #pragma unroll
        for (int j = 0; j < 8; ++j) zp[base + t + j * 256] = z;
    } else {                                // blocks 569..600 zero h: 65536 f4 / 32
        float4* zp = (float4*)(ws + WS_H);
        float4 z = {0.f,0.f,0.f,0.f};
        int base = (blk - 569) * 2048;
        #pragma unroll
        for (int j = 0; j < 8; ++j) zp[base + t + j * 256] = z;
    }
}

// block-wide (sm,ss) reduction, 256 threads
__device__ inline void red2(float& sm, float& ss) {
    for (int off = 32; off; off >>= 1) {
        sm += __shfl_xor(sm, off, 64);
        ss += __shfl_xor(ss, off, 64);
    }
    __shared__ float ra[4], rb[4];
    int wv = threadIdx.x >> 6, lane = threadIdx.x & 63;
    if (lane == 0) { ra[wv] = sm; rb[wv] = ss; }
    __syncthreads();
    sm = ra[0] + ra[1] + ra[2] + ra[3];
    ss = rb[0] + rb[1] + rb[2] + rb[3];
}

// TAIL ids: 0 none, 1 LN1(sbuf->y), 2 scan(qkv->imv), 3 LN2 in-place(sbuf),
//           4 gelu(h)+zero sbuf, 5 sbuf+=fc2_b then LN1->y (or ->outF at a==2)
// Sync protocol (fence-hygiene version):
//   producer: epilogue atomicAdds (agent scope, land at LLC) -> __syncthreads()
//             (compiler emits s_waitcnt vmcnt(0) before s_barrier, so all the
//             block's atomics are globally visible) -> RELAXED fetch_add.
//             No __threadfence: no wbl2/inv storm.
//   consumer: RELAXED spin (plain LLC polls, no invalidate per iteration),
//             then ONE ACQUIRE load (single buffer_inv to drop clean-stale L2
//             copies of the atomically-updated lines) -> __syncthreads -> tail.
template<int NIT, int TAIL>
__global__ __launch_bounds__(256) void k_gemm(P p) {
    int t = threadIdx.x;

    if ((int)blockIdx.y >= p.NS) {          // zero-extra blocks
        int per = (p.z4 + p.NX - 1) / p.NX;
        float4* zp = (float4*)p.zbuf;
        float4 z = {0.f,0.f,0.f,0.f};
        int base = blockIdx.x * per, end = min(base + per, p.z4);
        for (int i = base + t; i < end; i += 256) zp[i] = z;
        return;
    }

    {   // ---- GEMM phase (unchanged core) ----
        int lane = t & 63, wv = t >> 6;
        int m = lane & 15, q = lane >> 4;
        int nb = blockIdx.x * 64 + wv * 16;
        int K = p.K, N = p.N;
        size_t kbeg = (size_t)blockIdx.y * (NIT * 32);
        const float* A0 = p.A + (size_t)m * K + kbeg + q * 8;
        const float* A1 = A0 + (size_t)16 * K;
        const float* B  = p.W + (size_t)(nb + m) * K + kbeg + q * 8;
        f32x4 acc0 = {0.f,0.f,0.f,0.f};
        f32x4 acc1 = {0.f,0.f,0.f,0.f};
        float4 a0l = *(const float4*)(A0);
        float4 a0h = *(const float4*)(A0 + 4);
        float4 a1l = *(const float4*)(A1);
        float4 a1h = *(const float4*)(A1 + 4);
        float4 bl  = *(const float4*)(B);
        float4 bh  = *(const float4*)(B + 4);
        #pragma unroll
        for (int it = 0; it < NIT; ++it) {
            float4 c0l = a0l, c0h = a0h, c1l = a1l, c1h = a1h, cbl = bl, cbh = bh;
            if (it + 1 < NIT) {
                int k = (it + 1) * 32;
                a0l = *(const float4*)(A0 + k);
                a0h = *(const float4*)(A0 + k + 4);
                a1l = *(const float4*)(A1 + k);
                a1h = *(const float4*)(A1 + k + 4);
                bl  = *(const float4*)(B + k);
                bh  = *(const float4*)(B + k + 4);
            }
            bf16x8 fa0 = { f2bf(c0l.x), f2bf(c0l.y), f2bf(c0l.z), f2bf(c0l.w),
                           f2bf(c0h.x), f2bf(c0h.y), f2bf(c0h.z), f2bf(c0h.w) };
            bf16x8 fa1 = { f2bf(c1l.x), f2bf(c1l.y), f2bf(c1l.z), f2bf(c1l.w),
                           f2bf(c1h.x), f2bf(c1h.y), f2bf(c1h.z), f2bf(c1h.w) };
            bf16x8 fb  = { f2bf(cbl.x), f2bf(cbl.y), f2bf(cbl.z), f2bf(cbl.w),
                           f2bf(cbh.x), f2bf(cbh.y), f2bf(cbh.z), f2bf(cbh.w) };
            acc0 = __builtin_amdgcn_mfma_f32_16x16x32_bf16(fa0, fb, acc0, 0, 0, 0);
            acc1 = __builtin_amdgcn_mfma_f32_16x16x32_bf16(fa1, fb, acc1, 0, 0, 0);
        }
        float* op = p.out + (size_t)(q * 4) * N + nb + m;
        #pragma unroll
        for (int r = 0; r < 4; ++r) {
            atomicAdd(op + (size_t)r * N, acc0[r]);
            atomicAdd(op + (size_t)(r + 16) * N, acc1[r]);
        }
    }

    // ---- release: barrier (implies vmcnt(0)) + relaxed count. NO threadfence. ----
    __syncthreads();
    if (t == 0)
        __hip_atomic_fetch_add(p.cnt, 1, __ATOMIC_RELAXED, __HIP_MEMORY_SCOPE_AGENT);
    if (TAIL == 0) return;

    constexpr int NTAIL = (TAIL == 2) ? 16 : (TAIL == 4) ? 64 : 32;
    if (blockIdx.y != 0 || (int)blockIdx.x >= NTAIL) return;

    // ---- acquire: relaxed spin, then one acquire load ----
    int target = p.NX * p.NS;
    if (t == 0) {
        while (__hip_atomic_load(p.cnt, __ATOMIC_RELAXED, __HIP_MEMORY_SCOPE_AGENT) < target)
            __builtin_amdgcn_s_sleep(8);
        (void)__hip_atomic_load(p.cnt, __ATOMIC_ACQUIRE, __HIP_MEMORY_SCOPE_AGENT);
    }
    __syncthreads();

    // ---- tail work ----
    if (TAIL == 1 || TAIL == 3 || TAIL == 5) {      // per-row LN variants
        int r = blockIdx.x;
        const float* row = p.sbuf + r * 2048;
        float vv[8], sm = 0.f, ss = 0.f;
        #pragma unroll
        for (int j = 0; j < 8; ++j) {
            int idx = t + j * 256;
            float v = row[idx];
            if (TAIL == 5) v += p.fc2_b[idx];
            vv[j] = v; sm += v; ss += v * v;
        }
        red2(sm, ss);
        float mu = sm * (1.0f / 2048.0f);
        float rstd = rsqrtf(ss * (1.0f / 2048.0f) - mu * mu + 1e-5f);
        if (TAIL == 5 && p.a == 2) {
            #pragma unroll
            for (int j = 0; j < 8; ++j) p.outF[r * 2048 + t + j * 256] = vv[j];
        } else {
            #pragma unroll
            for (int j = 0; j < 8; ++j) {
                int idx = t + j * 256;
                float v = vv[j];
                float ln1 = (v - mu) * rstd * p.g1[idx] + p.b1[idx];
                if (TAIL == 1) p.y[r * 2048 + idx] = ln1;
                if (TAIL == 3) p.sbuf[r * 2048 + idx] = (v - mu) * rstd * p.g2[idx] + p.b2[idx] + v;
                if (TAIL == 5) { p.sbuf[r * 2048 + idx] = v; p.y[r * 2048 + idx] = ln1; }
            }
        }
    }
    if (TAIL == 2) {                                 // scalar attn + serial scan
        int hd = blockIdx.x;
        __shared__ float rsa[32];
        if (t < 32) {
            const float* qr = p.qkv + (size_t)t * 6144 + hd * 128;
            const float* kr = qr + 2048;
            float acc = 0.f;
            for (int d = 0; d < 128; ++d) acc += qr[d] * kr[d];
            rsa[t] = acc * 0.08838834764831845f;
        }
        __syncthreads();
        if (t < 128) {
            float acc = 0.f;
            for (int i = 0; i < 32; ++i) {
                acc += rsa[i] * p.qkv[(size_t)i * 6144 + 4096 + hd * 128 + t];
                p.imv[i * 2048 + hd * 128 + t] = acc;
            }
        }
    }
    if (TAIL == 4) {                                 // gelu(h+fc1_b) + zero sbuf
        int b = blockIdx.x;
        size_t base = (size_t)b * 4096;
        #pragma unroll
        for (int j = 0; j < 16; ++j) {
            size_t idx = base + t + j * 256;
            float v = p.h[idx] + p.fc1_b[idx & 8191];
            p.h[idx] = 0.5f * v * (1.0f + erff(v * 0.70710678118654752f));
        }
        float4* zp = (float4*)p.sbuf;
        float4 z = {0.f,0.f,0.f,0.f};
        zp[b * 256 + t] = z;
    }
}

extern "C" void kernel_launch(void* const* d_in, const int* in_sizes, int n_in,
                              void* d_out, int out_size, void* d_ws, size_t ws_size,
                              hipStream_t stream) {
    const float* x      = (const float*)d_in[0];
    const float* weight = (const float*)d_in[1];
    const float* Wqkv   = (const float*)d_in[2];
    const float* Wo     = (const float*)d_in[3];
    const float* ln1_g  = (const float*)d_in[4];
    const float* ln1_b  = (const float*)d_in[5];
    const float* ln2_g  = (const float*)d_in[6];
    const float* ln2_b  = (const float*)d_in[7];
    const float* fc1_w  = (const float*)d_in[8];
    const float* fc1_b  = (const float*)d_in[9];
    const float* fc2_w  = (const float*)d_in[10];
    const float* fc2_b  = (const float*)d_in[11];
    float* ws = (float*)d_ws;
    int* cnt = (int*)(ws + WS_CNT);

    P base{};
    base.g1 = ln1_g; base.b1 = ln1_b; base.g2 = ln2_g; base.b2 = ln2_b;
    base.fc1_b = fc1_b; base.fc2_b = fc2_b;
    base.sbuf = ws + WS_SBUF; base.y = ws + WS_Y; base.qkv = ws + WS_QKV;
    base.imv = ws + WS_IMV; base.h = ws + WS_H; base.outF = (float*)d_out;

    k_init<<<601, 256, 0, stream>>>(x, ws);

    P p = base;                                     // D1: s += weight @ altx ; tail LN1
    p.W = weight; p.A = ws + WS_ALTX; p.out = ws + WS_SBUF;
    p.N = 2048; p.K = 2048; p.NX = 32; p.NS = 8; p.cnt = cnt + 0; p.z4 = 0;
    k_gemm<8, 1><<<dim3(32, 8), 256, 0, stream>>>(p);

    for (int a = 0; a < 3; ++a) {
        P q = base; q.a = a;                        // D2: qkv += Wqkv @ y ; tail scan ; extra: zero h (a>0)
        q.W = Wqkv + (size_t)a * 12582912; q.A = ws + WS_Y; q.out = ws + WS_QKV;
        q.N = 6144; q.K = 2048; q.NX = 96; q.NS = 8; q.cnt = cnt + 1 + a * 4;
        q.zbuf = ws + WS_H; q.z4 = (a > 0) ? 65536 : 0;
        k_gemm<8, 2><<<dim3(96, 8 + (q.z4 ? 1 : 0)), 256, 0, stream>>>(q);

        P w = base; w.a = a;                        // D3: sbuf += Wo @ imv ; tail LN2-residual
        w.W = Wo + (size_t)a * 4194304; w.A = ws + WS_IMV; w.out = ws + WS_SBUF;
        w.N = 2048; w.K = 2048; w.NX = 32; w.NS = 8; w.cnt = cnt + 2 + a * 4; w.z4 = 0;
        k_gemm<8, 3><<<dim3(32, 8), 256, 0, stream>>>(w);

        P f1 = base; f1.a = a;                      // D4: h += fc1 @ sbuf ; tail gelu+zero sbuf ; extra: zero qkv (a<2)
        f1.W = fc1_w; f1.A = ws + WS_SBUF; f1.out = ws + WS_H;
        f1.N = 8192; f1.K = 2048; f1.NX = 128; f1.NS = 8; f1.cnt = cnt + 3 + a * 4;
        f1.zbuf = ws + WS_QKV; f1.z4 = (a < 2) ? 49152 : 0;
        k_gemm<8, 4><<<dim3(128, 8 + (f1.z4 ? 1 : 0)), 256, 0, stream>>>(f1);

        P f2 = base; f2.a = a;                      // D5: sbuf += fc2 @ h ; tail bias(+LN1 or out)
        f2.W = fc2_w; f2.A = ws + WS_H; f2.out = ws + WS_SBUF;
        f2.N = 2048; f2.K = 8192; f2.NX = 32; f2.NS = 32; f2.cnt = cnt + 4 + a * 4; f2.z4 = 0;
        k_gemm<8, 5><<<dim3(32, 32), 256, 0, stream>>>(f2);
    }
}

// Round 5
// 552.673 us; speedup vs baseline: 2.1661x; 1.4717x over previous
//
#include <hip/hip_runtime.h>
#include <math.h>

typedef __attribute__((ext_vector_type(4))) float f32x4;
typedef __attribute__((ext_vector_type(8))) short bf16x8;

__device__ inline short f2bf(float f) {
    union { float f; unsigned u; } v; v.f = f;
    unsigned u = v.u;
    u += 0x7fffu + ((u >> 16) & 1u);   // RNE
    return (short)(u >> 16);
}

// ---------------- avgpool + sinusoidal bias init ----------------
__global__ __launch_bounds__(256) void k_avg_init(const float* __restrict__ x,
                                                  float* __restrict__ altx,
                                                  float* __restrict__ s) {
    int blk = blockIdx.x, t = threadIdx.x;
    if (blk < 512) {
        int wv = t >> 6, lane = t & 63;
        int p = blk * 4 + wv;              // p = c2*64 + c1
        const float* row = x + (size_t)p * 2048;
        int c2 = p >> 6, c1 = p & 63;
        int m = c1 * 32 + c2;
        for (int seg = 0; seg < 32; ++seg) {
            float v = row[seg * 64 + lane];
            for (int off = 32; off; off >>= 1) v += __shfl_xor(v, off, 64);
            if (lane == 0) altx[seg * 2048 + m] = v * (1.0f / 64.0f);
        }
    } else {
        int i = blk - 512;
        const float kln = logf(10000.0f) / 1024.0f;
        for (int l = t; l < 2048; l += 256) {
            int c = l & ~1;
            float ang = (float)i * expf(-(float)c * kln);
            s[i * 2048 + l] = (l & 1) ? cosf(ang) : sinf(ang);
        }
    }
}

__device__ inline void row_stats(const float* __restrict__ row, float& mu, float& rstd) {
    float sm = 0.f, ss = 0.f;
    for (int idx = threadIdx.x; idx < 2048; idx += 256) {
        float v = row[idx]; sm += v; ss += v * v;
    }
    for (int off = 32; off; off >>= 1) {
        sm += __shfl_xor(sm, off, 64);
        ss += __shfl_xor(ss, off, 64);
    }
    __shared__ float as[4], bs[4];
    int wv = threadIdx.x >> 6, lane = threadIdx.x & 63;
    if (lane == 0) { as[wv] = sm; bs[wv] = ss; }
    __syncthreads();
    sm = as[0] + as[1] + as[2] + as[3];
    ss = bs[0] + bs[1] + bs[2] + bs[3];
    mu = sm * (1.0f / 2048.0f);
    float var = ss * (1.0f / 2048.0f) - mu * mu;
    rstd = rsqrtf(var + 1e-5f);
}

// blocks 0..31: y = LN1(s).  blocks 32..55: zero qkv
__global__ __launch_bounds__(256) void k_prep1(const float* __restrict__ s,
                                               const float* __restrict__ g,
                                               const float* __restrict__ b,
                                               float* __restrict__ y,
                                               float* __restrict__ qkv) {
    int blk = blockIdx.x;
    if (blk < 32) {
        const float* row = s + blk * 2048;
        float mu, rstd; row_stats(row, mu, rstd);
        float* yr = y + blk * 2048;
        for (int idx = threadIdx.x; idx < 2048; idx += 256)
            yr[idx] = (row[idx] - mu) * rstd * g[idx] + b[idx];
    } else {
        int z = blk - 32;
        float4* p4 = (float4*)(qkv + (size_t)z * 8192);
        float4 zero = {0.f, 0.f, 0.f, 0.f};
        for (int idx = threadIdx.x; idx < 2048; idx += 256) p4[idx] = zero;
    }
}

// blocks 0..15: scalar attn + serial scan.  blocks 16..47: s2 = s
__global__ __launch_bounds__(256) void k_scan(const float* __restrict__ qkv,
                                              const float* __restrict__ s,
                                              float* __restrict__ imv,
                                              float* __restrict__ s2) {
    int blk = blockIdx.x, t = threadIdx.x;
    if (blk < 16) {
        int h = blk;
        __shared__ float rsa[32];
        if (t < 32) {
            const float* qr = qkv + (size_t)t * 6144 + h * 128;
            const float* kr = qr + 2048;
            float acc = 0.f;
            for (int d = 0; d < 128; ++d) acc += qr[d] * kr[d];
            rsa[t] = acc * 0.08838834764831845f;
        }
        __syncthreads();
        if (t < 128) {
            float acc = 0.f;
            for (int i = 0; i < 32; ++i) {
                acc += rsa[i] * qkv[(size_t)i * 6144 + 4096 + h * 128 + t];
                imv[i * 2048 + h * 128 + t] = acc;
            }
        }
    } else {
        int z = blk - 16;
        const float4* sp = (const float4*)(s + (size_t)z * 2048);
        float4* dp = (float4*)(s2 + (size_t)z * 2048);
        for (int idx = t; idx < 512; idx += 256) dp[idx] = sp[idx];
    }
}

// blocks 0..31: sout = LN2(s2)+s2.  blocks 32..63: zero h
__global__ __launch_bounds__(256) void k_prep2(const float* __restrict__ s2,
                                               const float* __restrict__ g,
                                               const float* __restrict__ b,
                                               float* __restrict__ sout,
                                               float* __restrict__ h) {
    int blk = blockIdx.x;
    if (blk < 32) {
        const float* row = s2 + blk * 2048;
        float mu, rstd; row_stats(row, mu, rstd);
        float* sr = sout + blk * 2048;
        for (int idx = threadIdx.x; idx < 2048; idx += 256) {
            float v = row[idx];
            sr[idx] = (v - mu) * rstd * g[idx] + b[idx] + v;
        }
    } else {
        int z = blk - 32;
        float4* p4 = (float4*)(h + (size_t)z * 8192);
        float4 zero = {0.f, 0.f, 0.f, 0.f};
        for (int idx = threadIdx.x; idx < 2048; idx += 256) p4[idx] = zero;
    }
}

// blocks 0..127: h = gelu(h + fc1_b).  blocks 128..159: sout = broadcast(fc2_b)
__global__ __launch_bounds__(256) void k_act(float* __restrict__ h,
                                             const float* __restrict__ fc1_b,
                                             float* __restrict__ sout,
                                             const float* __restrict__ fc2_b) {
    int blk = blockIdx.x, t = threadIdx.x;
    if (blk < 128) {
        size_t base = ((size_t)blk * 256 + t) * 8;
        #pragma unroll
        for (int j = 0; j < 8; ++j) {
            size_t idx = base + j;
            float v = h[idx] + fc1_b[idx & 8191];
            h[idx] = 0.5f * v * (1.0f + erff(v * 0.70710678118654752f));
        }
    } else {
        size_t base = ((size_t)(blk - 128) * 256 + t) * 8;
        #pragma unroll
        for (int j = 0; j < 8; ++j) {
            size_t idx = base + j;
            sout[idx] = fc2_b[idx & 2047];
        }
    }
}

// ---------------- skinny GEMM v2: out[32][N] += act[32][K] @ W[N][K]^T ----------------
// Per block: 64 output cols, k-slice of KC.  Structure built for MLP:
//   1. all threads issue A-stage global loads (32 x KC floats, oldest in vmcnt queue)
//   2. each wave issues ALL its B loads for the k-slice (2*S dwordx4 = up to 16KB
//      in flight per wave) — these ride behind the staging consume
//   3. convert A -> bf16, ds_write (waits only on the older A loads)
//   4. __syncthreads (drains B too, but B has had the full staging latency to arrive)
//   5. stall-free inner loop: ds_read_b128 A-frags + convert B regs + MFMA
// LDS: A staged as bf16 [32][KC+8] (row stride (KC+8)*2B, 16B-aligned frags,
// 2-way bank aliasing only = free).
template<int KC, int TAG>
__global__ __launch_bounds__(256, 2) void k_gemm(const float* __restrict__ W,
                                                 const float* __restrict__ act,
                                                 float* __restrict__ out,
                                                 int N, int K) {
    constexpr int S = KC / 32;            // MFMA k-steps
    __shared__ short lAs[32][KC + 8];
    int t = threadIdx.x;
    int lane = t & 63, wv = t >> 6;
    int m = lane & 15, q = lane >> 4;
    int nb = blockIdx.x * 64 + wv * 16;
    size_t kbeg = (size_t)blockIdx.y * KC;

    // --- 1. A-stage loads: thread t covers row t>>3, cols (t&7)*(KC/8).. ---
    constexpr int APT = KC / 8;           // floats per thread (8,16,32)
    int arow = t >> 3, acol = (t & 7) * APT;
    const float* ap = act + (size_t)arow * K + kbeg + acol;
    float4 areg[APT / 4];
    #pragma unroll
    for (int j = 0; j < APT / 4; ++j) areg[j] = *(const float4*)(ap + j * 4);

    // --- 2. B loads: lane covers row nb+m, cols s*32 + q*8 (+4) ---
    const float* B = W + (size_t)(nb + m) * K + kbeg + q * 8;
    float4 Bb[2 * S];
    #pragma unroll
    for (int s = 0; s < S; ++s) {
        Bb[2 * s]     = *(const float4*)(B + s * 32);
        Bb[2 * s + 1] = *(const float4*)(B + s * 32 + 4);
    }

    // --- 3. convert + stage A into LDS ---
    #pragma unroll
    for (int j = 0; j < APT / 4; ++j) {
        short4 c = { f2bf(areg[j].x), f2bf(areg[j].y), f2bf(areg[j].z), f2bf(areg[j].w) };
        *(short4*)&lAs[arow][acol + j * 4] = c;
    }
    __syncthreads();

    // --- 5. inner loop ---
    f32x4 acc0 = {0.f,0.f,0.f,0.f};
    f32x4 acc1 = {0.f,0.f,0.f,0.f};
    #pragma unroll
    for (int s = 0; s < S; ++s) {
        bf16x8 fa0 = *(const bf16x8*)&lAs[m][s * 32 + q * 8];
        bf16x8 fa1 = *(const bf16x8*)&lAs[m + 16][s * 32 + q * 8];
        float4 bl = Bb[2 * s], bh = Bb[2 * s + 1];
        bf16x8 fb = { f2bf(bl.x), f2bf(bl.y), f2bf(bl.z), f2bf(bl.w),
                      f2bf(bh.x), f2bf(bh.y), f2bf(bh.z), f2bf(bh.w) };
        acc0 = __builtin_amdgcn_mfma_f32_16x16x32_bf16(fa0, fb, acc0, 0, 0, 0);
        acc1 = __builtin_amdgcn_mfma_f32_16x16x32_bf16(fa1, fb, acc1, 0, 0, 0);
    }

    // C/D layout: col = lane&15 (n), row = q*4+reg (token)
    float* op = out + (size_t)(q * 4) * N + nb + m;
    #pragma unroll
    for (int r = 0; r < 4; ++r) {
        atomicAdd(op + (size_t)r * N, acc0[r]);
        atomicAdd(op + (size_t)(r + 16) * N, acc1[r]);
    }
}

extern "C" void kernel_launch(void* const* d_in, const int* in_sizes, int n_in,
                              void* d_out, int out_size, void* d_ws, size_t ws_size,
                              hipStream_t stream) {
    const float* x      = (const float*)d_in[0];
    const float* weight = (const float*)d_in[1];
    const float* Wqkv   = (const float*)d_in[2];
    const float* Wo     = (const float*)d_in[3];
    const float* ln1_g  = (const float*)d_in[4];
    const float* ln1_b  = (const float*)d_in[5];
    const float* ln2_g  = (const float*)d_in[6];
    const float* ln2_b  = (const float*)d_in[7];
    const float* fc1_w  = (const float*)d_in[8];
    const float* fc1_b  = (const float*)d_in[9];
    const float* fc2_w  = (const float*)d_in[10];
    const float* fc2_b  = (const float*)d_in[11];
    float* ws   = (float*)d_ws;
    float* altx = ws;                    // 65536 f
    float* sbuf = ws + 65536;            // 65536 f
    float* y    = ws + 131072;           // 65536 f
    float* s2   = ws + 196608;           // 65536 f
    float* imv  = ws + 262144;           // 65536 f
    float* qkv  = ws + 327680;           // 196608 f
    float* h    = ws + 524288;           // 262144 f
    float* outF = (float*)d_out;

    k_avg_init<<<544, 256, 0, stream>>>(x, altx, sbuf);
    k_gemm<128, 0><<<dim3(32, 16), 256, 0, stream>>>(weight, altx, sbuf, 2048, 2048);
    for (int a = 0; a < 3; ++a) {
        k_prep1<<<56, 256, 0, stream>>>(sbuf, ln1_g, ln1_b, y, qkv);
        k_gemm<128, 1><<<dim3(96, 16), 256, 0, stream>>>(Wqkv + (size_t)a * 12582912, y, qkv, 6144, 2048);
        k_scan<<<48, 256, 0, stream>>>(qkv, sbuf, imv, s2);
        k_gemm<128, 2><<<dim3(32, 16), 256, 0, stream>>>(Wo + (size_t)a * 4194304, imv, s2, 2048, 2048);
        k_prep2<<<64, 256, 0, stream>>>(s2, ln2_g, ln2_b, sbuf, h);
        k_gemm<128, 3><<<dim3(128, 16), 256, 0, stream>>>(fc1_w, sbuf, h, 8192, 2048);
        float* sout = (a == 2) ? outF : sbuf;
        k_act<<<160, 256, 0, stream>>>(h, fc1_b, sout, fc2_b);
        k_gemm<256, 4><<<dim3(32, 32), 256, 0, stream>>>(fc2_w, h, sout, 2048, 8192);
    }
}

// Round 6
// 552.584 us; speedup vs baseline: 2.1665x; 1.0002x over previous
//
#include <hip/hip_runtime.h>
#include <math.h>

typedef __attribute__((ext_vector_type(4))) float f32x4;
typedef __attribute__((ext_vector_type(8))) short bf16x8;

__device__ inline short f2bf(float f) {
    union { float f; unsigned u; } v; v.f = f;
    unsigned u = v.u;
    u += 0x7fffu + ((u >> 16) & 1u);   // RNE
    return (short)(u >> 16);
}

// ---------------- avgpool + sinusoidal bias init ----------------
__global__ __launch_bounds__(256) void k_avg_init(const float* __restrict__ x,
                                                  float* __restrict__ altx,
                                                  float* __restrict__ s) {
    int blk = blockIdx.x, t = threadIdx.x;
    if (blk < 512) {
        int wv = t >> 6, lane = t & 63;
        int p = blk * 4 + wv;              // p = c2*64 + c1
        const float* row = x + (size_t)p * 2048;
        int c2 = p >> 6, c1 = p & 63;
        int m = c1 * 32 + c2;
        for (int seg = 0; seg < 32; ++seg) {
            float v = row[seg * 64 + lane];
            for (int off = 32; off; off >>= 1) v += __shfl_xor(v, off, 64);
            if (lane == 0) altx[seg * 2048 + m] = v * (1.0f / 64.0f);
        }
    } else {
        int i = blk - 512;
        const float kln = logf(10000.0f) / 1024.0f;
        for (int l = t; l < 2048; l += 256) {
            int c = l & ~1;
            float ang = (float)i * expf(-(float)c * kln);
            s[i * 2048 + l] = (l & 1) ? cosf(ang) : sinf(ang);
        }
    }
}

__device__ inline void row_stats(const float* __restrict__ row, float& mu, float& rstd) {
    float sm = 0.f, ss = 0.f;
    for (int idx = threadIdx.x; idx < 2048; idx += 256) {
        float v = row[idx]; sm += v; ss += v * v;
    }
    for (int off = 32; off; off >>= 1) {
        sm += __shfl_xor(sm, off, 64);
        ss += __shfl_xor(ss, off, 64);
    }
    __shared__ float as[4], bs[4];
    int wv = threadIdx.x >> 6, lane = threadIdx.x & 63;
    if (lane == 0) { as[wv] = sm; bs[wv] = ss; }
    __syncthreads();
    sm = as[0] + as[1] + as[2] + as[3];
    ss = bs[0] + bs[1] + bs[2] + bs[3];
    mu = sm * (1.0f / 2048.0f);
    float var = ss * (1.0f / 2048.0f) - mu * mu;
    rstd = rsqrtf(var + 1e-5f);
}

// blocks 0..31: y = LN1(s) AND s2 = s (copy rides free).  blocks 32..55: zero qkv
__global__ __launch_bounds__(256) void k_prep1(const float* __restrict__ s,
                                               const float* __restrict__ g,
                                               const float* __restrict__ b,
                                               float* __restrict__ y,
                                               float* __restrict__ s2,
                                               float* __restrict__ qkv) {
    int blk = blockIdx.x;
    if (blk < 32) {
        const float* row = s + blk * 2048;
        float mu, rstd; row_stats(row, mu, rstd);
        float* yr = y + blk * 2048;
        float* cr = s2 + blk * 2048;
        for (int idx = threadIdx.x; idx < 2048; idx += 256) {
            float v = row[idx];
            yr[idx] = (v - mu) * rstd * g[idx] + b[idx];
            cr[idx] = v;
        }
    } else {
        int z = blk - 32;
        float4* p4 = (float4*)(qkv + (size_t)z * 8192);
        float4 zero = {0.f, 0.f, 0.f, 0.f};
        for (int idx = threadIdx.x; idx < 2048; idx += 256) p4[idx] = zero;
    }
}

// 16 blocks: per-head scalar attn + serial cumsum -> imv
__global__ __launch_bounds__(256) void k_scan(const float* __restrict__ qkv,
                                              float* __restrict__ imv) {
    int h = blockIdx.x, t = threadIdx.x;
    __shared__ float rsa[32];
    if (t < 32) {
        const float* qr = qkv + (size_t)t * 6144 + h * 128;
        const float* kr = qr + 2048;
        float acc = 0.f;
        for (int d = 0; d < 128; ++d) acc += qr[d] * kr[d];
        rsa[t] = acc * 0.08838834764831845f;   // 1/sqrt(128)
    }
    __syncthreads();
    if (t < 128) {
        float acc = 0.f;
        for (int i = 0; i < 32; ++i) {
            acc += rsa[i] * qkv[(size_t)i * 6144 + 4096 + h * 128 + t];
            imv[i * 2048 + h * 128 + t] = acc;
        }
    }
}

// blocks 0..31: sout = LN2(s2)+s2.  blocks 32..63: zero h
__global__ __launch_bounds__(256) void k_prep2(const float* __restrict__ s2,
                                               const float* __restrict__ g,
                                               const float* __restrict__ b,
                                               float* __restrict__ sout,
                                               float* __restrict__ h) {
    int blk = blockIdx.x;
    if (blk < 32) {
        const float* row = s2 + blk * 2048;
        float mu, rstd; row_stats(row, mu, rstd);
        float* sr = sout + blk * 2048;
        for (int idx = threadIdx.x; idx < 2048; idx += 256) {
            float v = row[idx];
            sr[idx] = (v - mu) * rstd * g[idx] + b[idx] + v;
        }
    } else {
        int z = blk - 32;
        float4* p4 = (float4*)(h + (size_t)z * 8192);
        float4 zero = {0.f, 0.f, 0.f, 0.f};
        for (int idx = threadIdx.x; idx < 2048; idx += 256) p4[idx] = zero;
    }
}

// blocks 0..127: h = gelu(h + fc1_b).  blocks 128..159: sout = broadcast(fc2_b)
__global__ __launch_bounds__(256) void k_act(float* __restrict__ h,
                                             const float* __restrict__ fc1_b,
                                             float* __restrict__ sout,
                                             const float* __restrict__ fc2_b) {
    int blk = blockIdx.x, t = threadIdx.x;
    if (blk < 128) {
        size_t base = ((size_t)blk * 256 + t) * 8;
        #pragma unroll
        for (int j = 0; j < 8; ++j) {
            size_t idx = base + j;
            float v = h[idx] + fc1_b[idx & 8191];
            h[idx] = 0.5f * v * (1.0f + erff(v * 0.70710678118654752f));
        }
    } else {
        size_t base = ((size_t)(blk - 128) * 256 + t) * 8;
        #pragma unroll
        for (int j = 0; j < 8; ++j) {
            size_t idx = base + j;
            sout[idx] = fc2_b[idx & 2047];
        }
    }
}

// ---------------- skinny GEMM v3: out[32][N] += act[32][K] @ W[N][K]^T ----------------
// Same v2 structure (upfront A+B burst, LDS-staged A, stall-free MFMA loop),
// now at 4 blocks/CU (launch_bounds(256,4)): four independent load bursts per CU
// stagger across each other's drain/compute/epilogue bubbles.
// KC=128 fixed: VGPR ~80 < 128 cap, LDS 8.7 KB (occupancy-safe).
template<int TAG>
__global__ __launch_bounds__(256, 4) void k_gemm(const float* __restrict__ W,
                                                 const float* __restrict__ act,
                                                 float* __restrict__ out,
                                                 int N, int K) {
    constexpr int KC = 128;
    constexpr int S = KC / 32;            // 4 MFMA k-steps
    __shared__ short lAs[32][KC + 8];
    int t = threadIdx.x;
    int lane = t & 63, wv = t >> 6;
    int m = lane & 15, q = lane >> 4;
    int nb = blockIdx.x * 64 + wv * 16;
    size_t kbeg = (size_t)blockIdx.y * KC;

    // --- A-stage loads: thread t covers row t>>3, 16 cols at (t&7)*16 ---
    constexpr int APT = KC / 8;           // 16 floats per thread
    int arow = t >> 3, acol = (t & 7) * APT;
    const float* ap = act + (size_t)arow * K + kbeg + acol;
    float4 areg[APT / 4];
    #pragma unroll
    for (int j = 0; j < APT / 4; ++j) areg[j] = *(const float4*)(ap + j * 4);

    // --- B loads: lane covers row nb+m, cols s*32 + q*8 (+4) ---
    const float* B = W + (size_t)(nb + m) * K + kbeg + q * 8;
    float4 Bb[2 * S];
    #pragma unroll
    for (int s = 0; s < S; ++s) {
        Bb[2 * s]     = *(const float4*)(B + s * 32);
        Bb[2 * s + 1] = *(const float4*)(B + s * 32 + 4);
    }

    // --- convert + stage A into LDS ---
    #pragma unroll
    for (int j = 0; j < APT / 4; ++j) {
        short4 c = { f2bf(areg[j].x), f2bf(areg[j].y), f2bf(areg[j].z), f2bf(areg[j].w) };
        *(short4*)&lAs[arow][acol + j * 4] = c;
    }
    __syncthreads();

    // --- inner loop ---
    f32x4 acc0 = {0.f,0.f,0.f,0.f};
    f32x4 acc1 = {0.f,0.f,0.f,0.f};
    #pragma unroll
    for (int s = 0; s < S; ++s) {
        bf16x8 fa0 = *(const bf16x8*)&lAs[m][s * 32 + q * 8];
        bf16x8 fa1 = *(const bf16x8*)&lAs[m + 16][s * 32 + q * 8];
        float4 bl = Bb[2 * s], bh = Bb[2 * s + 1];
        bf16x8 fb = { f2bf(bl.x), f2bf(bl.y), f2bf(bl.z), f2bf(bl.w),
                      f2bf(bh.x), f2bf(bh.y), f2bf(bh.z), f2bf(bh.w) };
        acc0 = __builtin_amdgcn_mfma_f32_16x16x32_bf16(fa0, fb, acc0, 0, 0, 0);
        acc1 = __builtin_amdgcn_mfma_f32_16x16x32_bf16(fa1, fb, acc1, 0, 0, 0);
    }

    // C/D layout: col = lane&15 (n), row = q*4+reg (token)
    float* op = out + (size_t)(q * 4) * N + nb + m;
    #pragma unroll
    for (int r = 0; r < 4; ++r) {
        atomicAdd(op + (size_t)r * N, acc0[r]);
        atomicAdd(op + (size_t)(r + 16) * N, acc1[r]);
    }
}

extern "C" void kernel_launch(void* const* d_in, const int* in_sizes, int n_in,
                              void* d_out, int out_size, void* d_ws, size_t ws_size,
                              hipStream_t stream) {
    const float* x      = (const float*)d_in[0];
    const float* weight = (const float*)d_in[1];
    const float* Wqkv   = (const float*)d_in[2];
    const float* Wo     = (const float*)d_in[3];
    const float* ln1_g  = (const float*)d_in[4];
    const float* ln1_b  = (const float*)d_in[5];
    const float* ln2_g  = (const float*)d_in[6];
    const float* ln2_b  = (const float*)d_in[7];
    const float* fc1_w  = (const float*)d_in[8];
    const float* fc1_b  = (const float*)d_in[9];
    const float* fc2_w  = (const float*)d_in[10];
    const float* fc2_b  = (const float*)d_in[11];
    float* ws   = (float*)d_ws;
    float* altx = ws;                    // 65536 f
    float* sbuf = ws + 65536;            // 65536 f
    float* y    = ws + 131072;           // 65536 f
    float* s2   = ws + 196608;           // 65536 f
    float* imv  = ws + 262144;           // 65536 f
    float* qkv  = ws + 327680;           // 196608 f
    float* h    = ws + 524288;           // 262144 f
    float* outF = (float*)d_out;

    k_avg_init<<<544, 256, 0, stream>>>(x, altx, sbuf);
    k_gemm<0><<<dim3(32, 16), 256, 0, stream>>>(weight, altx, sbuf, 2048, 2048);
    for (int a = 0; a < 3; ++a) {
        k_prep1<<<56, 256, 0, stream>>>(sbuf, ln1_g, ln1_b, y, s2, qkv);
        k_gemm<1><<<dim3(96, 16), 256, 0, stream>>>(Wqkv + (size_t)a * 12582912, y, qkv, 6144, 2048);
        k_scan<<<16, 256, 0, stream>>>(qkv, imv);
        k_gemm<2><<<dim3(32, 16), 256, 0, stream>>>(Wo + (size_t)a * 4194304, imv, s2, 2048, 2048);
        k_prep2<<<64, 256, 0, stream>>>(s2, ln2_g, ln2_b, sbuf, h);
        k_gemm<3><<<dim3(128, 16), 256, 0, stream>>>(fc1_w, sbuf, h, 8192, 2048);
        float* sout = (a == 2) ? outF : sbuf;
        k_act<<<160, 256, 0, stream>>>(h, fc1_b, sout, fc2_b);
        k_gemm<4><<<dim3(32, 64), 256, 0, stream>>>(fc2_w, h, sout, 2048, 8192);
    }
}